// Round 1
// baseline (1482.612 us; speedup 1.0000x reference)
//
#include <hip/hip_runtime.h>

// GCN 3-layer encoder: out = GCNconv3(relu(GCNconv2(relu(GCNconv1(x)))))
// GCNconv: out = D^{-1/2}(A+I)D^{-1/2}(X W) + b
// Refactor per layer:
//   y   = (X W) * dis[row]          (dis = rsqrt(deg), deg counts dst incl self-loop)
//   agg = y (self-loop) + scatter-add of y[src] into agg[dst]
//   out = agg * dis[row] + b  (+relu)

__global__ void deg_init_kernel(float* __restrict__ deg, int n) {
  int i = blockIdx.x * blockDim.x + threadIdx.x;
  if (i < n) deg[i] = 1.0f;  // self-loop contribution
}

__global__ void deg_count_kernel(const int* __restrict__ dst, float* __restrict__ deg, int E) {
  int e = blockIdx.x * blockDim.x + threadIdx.x;
  if (e < E) atomicAdd(&deg[dst[e]], 1.0f);
}

__global__ void deg_fin_kernel(float* __restrict__ deg, int n) {
  int i = blockIdx.x * blockDim.x + threadIdx.x;
  if (i < n) deg[i] = rsqrtf(deg[i]);  // deg >= 1 always
}

// X[n x K] @ W[K x M], scale row by dis[row]; write y and init agg=y (self loop).
template <int K, int M>
__global__ void gemm_scale_kernel(const float* __restrict__ X, const float* __restrict__ W,
                                  const float* __restrict__ dis, float* __restrict__ y,
                                  float* __restrict__ agg, int n) {
  __shared__ float sW[K * M];
  for (int i = threadIdx.x; i < K * M; i += blockDim.x) sW[i] = W[i];
  __syncthreads();
  constexpr int ROWS = 256 / M;  // 4 rows/block for M=64, 2 for M=128
  int row = blockIdx.x * ROWS + (int)(threadIdx.x / M);
  int col = threadIdx.x % M;
  if (row >= n) return;
  const float* xr = X + (size_t)row * K;
  float acc = 0.0f;
#pragma unroll
  for (int k = 0; k < K; ++k) acc = fmaf(xr[k], sW[k * M + col], acc);
  float v = acc * dis[row];
  size_t o = (size_t)row * M + col;
  y[o] = v;
  agg[o] = v;
}

// One 64-lane wave per edge: agg[dst] += y[src] (feature-parallel across lanes).
template <int M>
__global__ void scatter_kernel(const int* __restrict__ src, const int* __restrict__ dst,
                               const float* __restrict__ y, float* __restrict__ agg, int E) {
  int e = blockIdx.x * (blockDim.x >> 6) + (threadIdx.x >> 6);
  int lane = threadIdx.x & 63;
  if (e >= E) return;
  int s = src[e];
  int d = dst[e];
  const float* ys = y + (size_t)s * M;
  float* ad = agg + (size_t)d * M;
#pragma unroll
  for (int j = lane; j < M; j += 64) {
    atomicAdd(&ad[j], ys[j]);
  }
}

template <int M, bool RELU>
__global__ void finalize_kernel(const float* __restrict__ agg, const float* __restrict__ dis,
                                const float* __restrict__ b, float* __restrict__ out, int n) {
  int idx = blockIdx.x * blockDim.x + threadIdx.x;
  if (idx >= n * M) return;
  int row = idx / M;
  int col = idx % M;
  float v = agg[idx] * dis[row] + b[col];
  if (RELU) v = fmaxf(v, 0.0f);
  out[idx] = v;
}

extern "C" void kernel_launch(void* const* d_in, const int* in_sizes, int n_in,
                              void* d_out, int out_size, void* d_ws, size_t ws_size,
                              hipStream_t stream) {
  const float* x  = (const float*)d_in[0];
  const float* W1 = (const float*)d_in[1];
  const float* b1 = (const float*)d_in[2];
  const float* W2 = (const float*)d_in[3];
  const float* b2 = (const float*)d_in[4];
  const float* W3 = (const float*)d_in[5];
  const float* b3 = (const float*)d_in[6];
  const int*   ei = (const int*)d_in[7];

  const int n = in_sizes[0] / 64;   // 100000
  const int E = in_sizes[7] / 2;    // 1000000
  const int* src = ei;              // edge_index[0]
  const int* dst = ei + E;          // edge_index[1]

  // Workspace layout (fp32): dis[n] | bufA[n*128] | bufH[n*64]  (~77 MB)
  float* dis   = (float*)d_ws;
  float* bufA  = dis + n;
  float* bufH  = bufA + (size_t)n * 128;
  float* y12   = bufA;                    // layers 1-2: y in first n*64
  float* agg12 = bufA + (size_t)n * 64;   // layers 1-2: agg in second n*64
  float* out   = (float*)d_out;           // layer 3: agg lives in d_out

  dim3 blk(256);
  int gN  = (n + 255) / 256;
  int gE  = (E + 255) / 256;
  int gE4 = (E + 3) / 4;  // 4 edges (waves) per 256-thread block

  // degree -> dis = rsqrt(deg)
  deg_init_kernel<<<gN, blk, 0, stream>>>(dis, n);
  deg_count_kernel<<<gE, blk, 0, stream>>>(dst, dis, E);
  deg_fin_kernel<<<gN, blk, 0, stream>>>(dis, n);

  // Layer 1: x[ n x 64 ] @ W1[64x64] -> relu
  gemm_scale_kernel<64, 64><<<(n + 3) / 4, blk, 0, stream>>>(x, W1, dis, y12, agg12, n);
  scatter_kernel<64><<<gE4, blk, 0, stream>>>(src, dst, y12, agg12, E);
  finalize_kernel<64, true><<<(n * 64 + 255) / 256, blk, 0, stream>>>(agg12, dis, b1, bufH, n);

  // Layer 2: h[ n x 64 ] @ W2[64x64] -> relu
  gemm_scale_kernel<64, 64><<<(n + 3) / 4, blk, 0, stream>>>(bufH, W2, dis, y12, agg12, n);
  scatter_kernel<64><<<gE4, blk, 0, stream>>>(src, dst, y12, agg12, E);
  finalize_kernel<64, true><<<(n * 64 + 255) / 256, blk, 0, stream>>>(agg12, dis, b2, bufH, n);

  // Layer 3: h[ n x 64 ] @ W3[64x128] -> out (no relu)
  gemm_scale_kernel<64, 128><<<(n + 1) / 2, blk, 0, stream>>>(bufH, W3, dis, bufA, out, n);
  scatter_kernel<128><<<gE4, blk, 0, stream>>>(src, dst, bufA, out, E);
  finalize_kernel<128, false><<<(n * 128 + 255) / 256, blk, 0, stream>>>(out, dis, b3, out, n);
}

// Round 2
// 882.097 us; speedup vs baseline: 1.6808x; 1.6808x over previous
//
#include <hip/hip_runtime.h>

// GCN 3-layer encoder. Per layer:
//   y   = (X W) * dis[row]                      (dis = rsqrt(deg), deg incl self-loop)
//   out = (y[d] + sum_{e: s->d} y[s]) * dis[d] + b   (+relu)
// Aggregation via per-call CSR build (histogram -> scan -> fill), then
// gather-per-node (wave per node, lane = feature). No fp32 atomics.

// ---------------- CSR build ----------------

__global__ void hist_kernel(const int* __restrict__ dst, int* __restrict__ deg, int E) {
  int e = blockIdx.x * blockDim.x + threadIdx.x;
  if (e < E) atomicAdd(&deg[dst[e]], 1);
}

// Per-block exclusive scan (256 elems); writes per-elem exclusive partials + block sums.
__global__ void scanA_kernel(const int* __restrict__ deg, int* __restrict__ partial,
                             int* __restrict__ bsum, int n) {
  __shared__ int tmp[256];
  int t = threadIdx.x;
  int i = blockIdx.x * 256 + t;
  int v = (i < n) ? deg[i] : 0;
  tmp[t] = v;
  __syncthreads();
  for (int off = 1; off < 256; off <<= 1) {
    int a = (t >= off) ? tmp[t - off] : 0;
    __syncthreads();
    tmp[t] += a;
    __syncthreads();
  }
  if (i < n) partial[i] = tmp[t] - v;  // exclusive
  if (t == 255) bsum[blockIdx.x] = tmp[t];
}

// Single-block exclusive scan of block sums (nb <= 512).
__global__ void scanB_kernel(const int* __restrict__ bsum, int* __restrict__ boff, int nb) {
  __shared__ int tmp[512];
  int t = threadIdx.x;
  int v = (t < nb) ? bsum[t] : 0;
  tmp[t] = v;
  __syncthreads();
  for (int off = 1; off < 512; off <<= 1) {
    int a = (t >= off) ? tmp[t - off] : 0;
    __syncthreads();
    tmp[t] += a;
    __syncthreads();
  }
  if (t < nb) boff[t] = tmp[t] - v;  // exclusive
}

// row_ptr / cursor / dis finalize.
__global__ void scanC_kernel(const int* __restrict__ partial, const int* __restrict__ boff,
                             const int* __restrict__ deg, int* __restrict__ row_ptr,
                             int* __restrict__ cursor, float* __restrict__ dis, int n, int E) {
  int i = blockIdx.x * blockDim.x + threadIdx.x;
  if (i < n) {
    int rp = partial[i] + boff[i >> 8];
    row_ptr[i] = rp;
    cursor[i] = rp;
    dis[i] = rsqrtf((float)deg[i] + 1.0f);  // +1 = self-loop
  } else if (i == n) {
    row_ptr[n] = E;
  }
}

__global__ void fill_kernel(const int* __restrict__ src, const int* __restrict__ dst,
                            int* __restrict__ cursor, int* __restrict__ csr_src, int E) {
  int e = blockIdx.x * blockDim.x + threadIdx.x;
  if (e < E) {
    int pos = atomicAdd(&cursor[dst[e]], 1);
    csr_src[pos] = src[e];
  }
}

// ---------------- per-layer kernels ----------------

// X[n x K] @ W[K x M], scale row by dis[row] -> y.
template <int K, int M>
__global__ void gemm_scale_kernel(const float* __restrict__ X, const float* __restrict__ W,
                                  const float* __restrict__ dis, float* __restrict__ y, int n) {
  __shared__ float sW[K * M];
  for (int i = threadIdx.x; i < K * M; i += blockDim.x) sW[i] = W[i];
  __syncthreads();
  constexpr int ROWS = 256 / M;
  int row = blockIdx.x * ROWS + (int)(threadIdx.x / M);
  int col = threadIdx.x % M;
  if (row >= n) return;
  const float* xr = X + (size_t)row * K;
  float acc = 0.0f;
#pragma unroll
  for (int k = 0; k < K; ++k) acc = fmaf(xr[k], sW[k * M + col], acc);
  y[(size_t)row * M + col] = acc * dis[row];
}

// One wave per node: out[d] = (y[d] + sum y[s]) * dis[d] + b  (+relu).
template <int M, bool RELU>
__global__ void gather_kernel(const int* __restrict__ row_ptr, const int* __restrict__ csr_src,
                              const float* __restrict__ y, const float* __restrict__ dis,
                              const float* __restrict__ b, float* __restrict__ out, int n) {
  int node = blockIdx.x * (blockDim.x >> 6) + (threadIdx.x >> 6);
  int lane = threadIdx.x & 63;
  if (node >= n) return;
  int beg = row_ptr[node];
  int end = row_ptr[node + 1];
  float acc0 = y[(size_t)node * M + lane];  // self-loop
  float acc1 = 0.0f;
  if (M == 128) acc1 = y[(size_t)node * M + 64 + lane];
  int k = beg;
  for (; k + 1 < end; k += 2) {  // 2-edge unroll for MLP
    int s0 = csr_src[k];
    int s1 = csr_src[k + 1];
    acc0 += y[(size_t)s0 * M + lane];
    if (M == 128) acc1 += y[(size_t)s0 * M + 64 + lane];
    acc0 += y[(size_t)s1 * M + lane];
    if (M == 128) acc1 += y[(size_t)s1 * M + 64 + lane];
  }
  if (k < end) {
    int s0 = csr_src[k];
    acc0 += y[(size_t)s0 * M + lane];
    if (M == 128) acc1 += y[(size_t)s0 * M + 64 + lane];
  }
  float sc = dis[node];
  float v0 = acc0 * sc + b[lane];
  if (RELU) v0 = fmaxf(v0, 0.0f);
  out[(size_t)node * M + lane] = v0;
  if (M == 128) {
    float v1 = acc1 * sc + b[64 + lane];
    if (RELU) v1 = fmaxf(v1, 0.0f);
    out[(size_t)node * M + 64 + lane] = v1;
  }
}

// ---------------- launch ----------------

extern "C" void kernel_launch(void* const* d_in, const int* in_sizes, int n_in,
                              void* d_out, int out_size, void* d_ws, size_t ws_size,
                              hipStream_t stream) {
  const float* x  = (const float*)d_in[0];
  const float* W1 = (const float*)d_in[1];
  const float* b1 = (const float*)d_in[2];
  const float* W2 = (const float*)d_in[3];
  const float* b2 = (const float*)d_in[4];
  const float* W3 = (const float*)d_in[5];
  const float* b3 = (const float*)d_in[6];
  const int*   ei = (const int*)d_in[7];

  const int n = in_sizes[0] / 64;   // 100000
  const int E = in_sizes[7] / 2;    // 1000000
  const int* src = ei;
  const int* dst = ei + E;

  // Workspace layout:
  //   floats: dis[n] | y[n*128] | h[n*64]
  //   ints:   deg[n] | partial[n] | bsum[512] | boff[512] | row_ptr[n+1] | cursor[n] | csr_src[E]
  float* dis = (float*)d_ws;
  float* y   = dis + n;
  float* h   = y + (size_t)n * 128;
  int* deg     = (int*)(h + (size_t)n * 64);
  int* partial = deg + n;
  int* bsum    = partial + n;
  int* boff    = bsum + 512;
  int* row_ptr = boff + 512;
  int* cursor  = row_ptr + (n + 1);
  int* csr_src = cursor + n;
  float* out = (float*)d_out;

  dim3 blk(256);
  int gN  = (n + 255) / 256;        // 391 blocks
  int gN1 = (n + 256) / 256;        // covers i == n
  int gE  = (E + 255) / 256;
  int gW  = (n + 3) / 4;            // 4 waves (nodes) per block

  // --- CSR build + dis ---
  hipMemsetAsync(deg, 0, (size_t)n * sizeof(int), stream);
  hist_kernel<<<gE, blk, 0, stream>>>(dst, deg, E);
  scanA_kernel<<<gN, blk, 0, stream>>>(deg, partial, bsum, n);
  scanB_kernel<<<1, 512, 0, stream>>>(bsum, boff, gN);
  scanC_kernel<<<gN1, blk, 0, stream>>>(partial, boff, deg, row_ptr, cursor, dis, n, E);
  fill_kernel<<<gE, blk, 0, stream>>>(src, dst, cursor, csr_src, E);

  // --- Layer 1: x @ W1 -> relu -> h ---
  gemm_scale_kernel<64, 64><<<(n + 3) / 4, blk, 0, stream>>>(x, W1, dis, y, n);
  gather_kernel<64, true><<<gW, blk, 0, stream>>>(row_ptr, csr_src, y, dis, b1, h, n);

  // --- Layer 2: h @ W2 -> relu -> h ---
  gemm_scale_kernel<64, 64><<<(n + 3) / 4, blk, 0, stream>>>(h, W2, dis, y, n);
  gather_kernel<64, true><<<gW, blk, 0, stream>>>(row_ptr, csr_src, y, dis, b2, h, n);

  // --- Layer 3: h @ W3 -> out ---
  gemm_scale_kernel<64, 128><<<(n + 1) / 2, blk, 0, stream>>>(h, W3, dis, y, n);
  gather_kernel<128, false><<<gW, blk, 0, stream>>>(row_ptr, csr_src, y, dis, b3, out, n);
}